// Round 1
// baseline (96.798 us; speedup 1.0000x reference)
//
#include <hip/hip_runtime.h>

// Damped electrostatics with shifted-force cutoff.
// One thread per edge; gathers of per-atom data hit L2/L3 (5.2 MB total).

#define CUTOFF      10.0f
#define KEHALF      7.199822675975274f
#define OFFSET2     1.0f

__global__ __launch_bounds__(256) void damped_elec_kernel(
    const float* __restrict__ q,      // [N]
    const float* __restrict__ dip,    // [N,3]
    const float* __restrict__ quad,   // [N,9]
    const float* __restrict__ vec,    // [E,3]
    const float* __restrict__ dist,   // [E]
    const int*   __restrict__ idx_u,  // [E]
    const int*   __restrict__ idx_v,  // [E]
    float*       __restrict__ out,    // [E]
    int E)
{
    int i = blockIdx.x * blockDim.x + threadIdx.x;
    int stride = gridDim.x * blockDim.x;
    for (; i < E; i += stride) {
        float d  = dist[i];
        float vx = vec[3 * (size_t)i + 0];
        float vy = vec[3 * (size_t)i + 1];
        float vz = vec[3 * (size_t)i + 2];
        int u = idx_u[i];
        int v = idx_v[i];

        float qu = q[u];
        float qv = q[v];

        float inv_d = 1.0f / d;
        float d_damped = sqrtf(d * d + OFFSET2);

        // poly5 switch, cutoff_sr = 4
        float x = d * 0.25f;
        float sw = 0.0f;
        if (x < 1.0f) {
            float x2 = x * x;
            float x3 = x2 * x;
            sw = 1.0f - x3 * (10.0f - 15.0f * x + 6.0f * x2);
        }
        float chi = sw / d_damped + (1.0f - sw) * inv_d;

        // shifted-force corrections (cutoff = 10)
        float chi_shift  = 0.2f    - 0.01f    * d;   // 2/C   - d/C^2
        float chi2_shift = 0.03f   - 0.002f   * d;   // 3/C^2 - 2d/C^3
        float chi3_shift = 0.004f  - 0.0003f  * d;   // 4/C^3 - 3d/C^4

        float chi2 = chi * chi;
        float chi3 = chi2 * chi;
        float c1 = chi  - chi_shift;
        float c2 = chi2 - chi2_shift;
        float c3 = chi3 - chi3_shift;

        float Ee = qu * qv * c1;

        // dipoles
        float du0 = dip[3 * (size_t)u + 0];
        float du1 = dip[3 * (size_t)u + 1];
        float du2 = dip[3 * (size_t)u + 2];
        float dv0 = dip[3 * (size_t)v + 0];
        float dv1 = dip[3 * (size_t)v + 1];
        float dv2 = dip[3 * (size_t)v + 2];

        float dot_uv = (vx * dv0 + vy * dv1 + vz * dv2) * inv_d;
        float dot_vu = (vx * du0 + vy * du1 + vz * du2) * inv_d;
        float dd     = du0 * dv0 + du1 * dv1 + du2 * dv2;

        Ee += 2.0f * qu * dot_uv * c2;
        Ee += (dd - 3.0f * dot_uv * dot_vu) * c3;

        // quadrupole of v: sum_ij traceless_ij * Q_ij
        //   traceless = (v v^T)/d^2 - (|v|^2/(3 d^2)) I, and |v| == d
        //   => sum = v^T Q v / d^2 - tr(Q)/3
        const float* Q = quad + 9 * (size_t)v;
        float q00 = Q[0], q01 = Q[1], q02 = Q[2];
        float q10 = Q[3], q11 = Q[4], q12 = Q[5];
        float q20 = Q[6], q21 = Q[7], q22 = Q[8];

        float vQv = vx * (q00 * vx + q01 * vy + q02 * vz)
                  + vy * (q10 * vx + q11 * vy + q12 * vz)
                  + vz * (q20 * vx + q21 * vy + q22 * vz);
        float trQ = q00 + q11 + q22;
        float inv_d2 = inv_d * inv_d;
        float sum_uv = vQv * inv_d2 - trQ * (1.0f / 3.0f);

        Ee += qu * sum_uv * c3;

        Ee *= KEHALF;
        out[i] = (d <= CUTOFF) ? Ee : 0.0f;
    }
}

extern "C" void kernel_launch(void* const* d_in, const int* in_sizes, int n_in,
                              void* d_out, int out_size, void* d_ws, size_t ws_size,
                              hipStream_t stream) {
    const float* q    = (const float*)d_in[0];  // atomic_charges      [N]
    const float* dip  = (const float*)d_in[1];  // atomic_dipoles      [N,3]
    const float* quad = (const float*)d_in[2];  // atomic_quadrupoles  [N,3,3]
    const float* vec  = (const float*)d_in[3];  // vectors_uv          [E,3]
    const float* dist = (const float*)d_in[4];  // distances_uv        [E]
    const int*   iu   = (const int*)d_in[5];    // idx_u               [E]
    const int*   iv   = (const int*)d_in[6];    // idx_v               [E]
    float* out = (float*)d_out;

    int E = in_sizes[4];
    int block = 256;
    int grid = (E + block - 1) / block;
    if (grid > 2048) grid = 2048;   // grid-stride covers the rest
    damped_elec_kernel<<<grid, block, 0, stream>>>(q, dip, quad, vec, dist, iu, iv, out, E);
}